// Round 5
// baseline (608.435 us; speedup 1.0000x reference)
//
#include <hip/hip_runtime.h>
#include <math.h>

#define N_NODES 100000
#define N_EDGES 1600000
#define IN_F    512
#define HID     128
#define NBLK    ((N_NODES + 255) / 256)   // 391 scan blocks

typedef __attribute__((ext_vector_type(8))) _Float16 half8;
typedef __attribute__((ext_vector_type(2))) _Float16 half2v;
typedef __attribute__((ext_vector_type(4))) float float4v;

// ---------------- pass A: per-XCD sharded degrees + local rank ----------------
// Each wave atomically updates only its own XCD's counter copy -> no cross-XCD
// line ping-pong. rank[e] = (xcc << 28) | local_rank.
__global__ void rank_kernel(const int* __restrict__ src, const int* __restrict__ dst,
                            int* __restrict__ outdeg8, int* __restrict__ indeg8,
                            int* __restrict__ rank) {
    unsigned xcc;
    asm volatile("s_getreg_b32 %0, hwreg(HW_REG_XCC_ID)" : "=s"(xcc));
    xcc &= 7;
    int e = blockIdx.x * blockDim.x + threadIdx.x;
    if (e < N_EDGES) {
        int s = src[e], d = dst[e];
        atomicAdd(&outdeg8[xcc * N_NODES + s], 1);
        int r = atomicAdd(&indeg8[xcc * N_NODES + d], 1);
        rank[e] = (int)((xcc << 28) | (unsigned)r);
    }
}

// ---------------- merge 8 copies: norms, per-copy bases, total indeg ----------------
__global__ void merge_kernel(const int* __restrict__ outdeg8, const int* __restrict__ indeg8,
                             float* __restrict__ norm_src, float* __restrict__ norm_dst,
                             int* __restrict__ cbase, int* __restrict__ indeg_tot) {
    int n = blockIdx.x * blockDim.x + threadIdx.x;
    if (n < N_NODES) {
        int so = 0, si = 0;
#pragma unroll
        for (int c = 0; c < 8; c++) {
            so += outdeg8[c * N_NODES + n];
            cbase[c * N_NODES + n] = si;
            si += indeg8[c * N_NODES + n];
        }
        norm_src[n] = rsqrtf(fmaxf((float)so, 1.0f));
        norm_dst[n] = rsqrtf(fmaxf((float)si, 1.0f));
        indeg_tot[n] = si;
    }
}

// ---------------- 3-kernel coalesced prefix scan of indeg_tot -> offs[N+1] ----------------
__global__ void scanA_kernel(const int* __restrict__ indeg, int* __restrict__ bsum) {
    __shared__ int sh[256];
    int t = threadIdx.x, idx = blockIdx.x * 256 + t;
    sh[t] = (idx < N_NODES) ? indeg[idx] : 0;
    __syncthreads();
#pragma unroll
    for (int d = 128; d > 0; d >>= 1) {
        if (t < d) sh[t] += sh[t + d];
        __syncthreads();
    }
    if (t == 0) bsum[blockIdx.x] = sh[0];
}

__global__ __launch_bounds__(512) void scanB_kernel(const int* __restrict__ bsum,
                                                    int* __restrict__ bbase) {
    __shared__ int sh[512];
    int t = threadIdx.x;
    sh[t] = (t < NBLK) ? bsum[t] : 0;
    __syncthreads();
#pragma unroll
    for (int d = 1; d < 512; d <<= 1) {
        int v = (t >= d) ? sh[t - d] : 0;
        __syncthreads();
        sh[t] += v;
        __syncthreads();
    }
    if (t < NBLK) bbase[t] = (t == 0) ? 0 : sh[t - 1];
}

__global__ void scanC_kernel(const int* __restrict__ indeg, const int* __restrict__ bbase,
                             int* __restrict__ offs) {
    __shared__ int sh[256];
    int t = threadIdx.x, idx = blockIdx.x * 256 + t;
    int v = (idx < N_NODES) ? indeg[idx] : 0;
    sh[t] = v;
    __syncthreads();
#pragma unroll
    for (int d = 1; d < 256; d <<= 1) {
        int u = (t >= d) ? sh[t - d] : 0;
        __syncthreads();
        sh[t] += u;
        __syncthreads();
    }
    int incl = sh[t];
    if (idx < N_NODES) {
        int base = bbase[blockIdx.x];
        offs[idx] = base + incl - v;
        if (idx == N_NODES - 1) offs[N_NODES] = base + incl;
    }
}

// ---------------- pass B: scatter src into CSR ----------------
__global__ void scatter_csr_kernel(const int* __restrict__ src, const int* __restrict__ dst,
                                   const int* __restrict__ rank, const int* __restrict__ offs,
                                   const int* __restrict__ cbase, int* __restrict__ csr) {
    int e = blockIdx.x * blockDim.x + threadIdx.x;
    if (e < N_EDGES) {
        int d = dst[e];
        unsigned r = (unsigned)rank[e];
        int x  = r >> 28;
        int rl = r & 0x0FFFFFFF;
        csr[offs[d] + cbase[x * N_NODES + d] + rl] = src[e];
    }
}

// ---------------- W1 -> f16, transposed to [col][k] ----------------
__global__ void cvtW1_kernel(const float* __restrict__ W1, _Float16* __restrict__ W1T) {
    int i = blockIdx.x * blockDim.x + threadIdx.x;
    if (i < IN_F * HID) {
        int k = i >> 7, c = i & 127;
        W1T[(size_t)c * IN_F + k] = (_Float16)W1[i];
    }
}

// ---------------- GEMM1 via MFMA f16, double-buffered, f16 output ----------------
#define APAD 40
__global__ __launch_bounds__(256) void gemm1_mfma_kernel(const float* __restrict__ X,
                                                         const _Float16* __restrict__ W1T,
                                                         const float* __restrict__ norm_src,
                                                         _Float16* __restrict__ xwh) {
    __shared__ _Float16 As[2][128 * APAD];

    const int t    = threadIdx.x;
    const int wave = t >> 6;
    const int lane = t & 63;
    const int m0   = blockIdx.x * 128;
    const int quad = lane >> 4;
    const int l16  = lane & 15;

    float4v acc[2][8];
#pragma unroll
    for (int r = 0; r < 2; r++)
#pragma unroll
        for (int c = 0; c < 8; c++) acc[r][c] = (float4v)0.f;

    const int srow = t >> 1;
    const int sc16 = (t & 1) * 16;
    const int sgrow = m0 + srow;
    const bool svalid = sgrow < N_NODES;
    const float* xbase = X + (size_t)sgrow * IN_F + sc16;

    float4 va[4];
#pragma unroll
    for (int i = 0; i < 4; i++) va[i] = make_float4(0.f, 0.f, 0.f, 0.f);
    if (svalid) {
        const float4* xp = reinterpret_cast<const float4*>(xbase);
        va[0] = xp[0]; va[1] = xp[1]; va[2] = xp[2]; va[3] = xp[3];
    }
    half8 bfrag[8];
#pragma unroll
    for (int ct = 0; ct < 8; ct++)
        bfrag[ct] = *reinterpret_cast<const half8*>(&W1T[(size_t)(ct * 16 + l16) * IN_F + quad * 8]);

    {
        half8 h0, h1;
        h0[0]=(_Float16)va[0].x; h0[1]=(_Float16)va[0].y; h0[2]=(_Float16)va[0].z; h0[3]=(_Float16)va[0].w;
        h0[4]=(_Float16)va[1].x; h0[5]=(_Float16)va[1].y; h0[6]=(_Float16)va[1].z; h0[7]=(_Float16)va[1].w;
        h1[0]=(_Float16)va[2].x; h1[1]=(_Float16)va[2].y; h1[2]=(_Float16)va[2].z; h1[3]=(_Float16)va[2].w;
        h1[4]=(_Float16)va[3].x; h1[5]=(_Float16)va[3].y; h1[6]=(_Float16)va[3].z; h1[7]=(_Float16)va[3].w;
        *reinterpret_cast<half8*>(&As[0][srow * APAD + sc16 + 0]) = h0;
        *reinterpret_cast<half8*>(&As[0][srow * APAD + sc16 + 8]) = h1;
    }

    int cur = 0;
    for (int it = 0; it < IN_F / 32; it++) {
        const int ktn = (it + 1) * 32;
        const bool more = ktn < IN_F;
        __syncthreads();

        float4 vb[4];
        half8 bnext[8];
        if (more) {
            if (svalid) {
                const float4* xp = reinterpret_cast<const float4*>(xbase + ktn);
                vb[0] = xp[0]; vb[1] = xp[1]; vb[2] = xp[2]; vb[3] = xp[3];
            } else {
                vb[0] = vb[1] = vb[2] = vb[3] = make_float4(0.f, 0.f, 0.f, 0.f);
            }
#pragma unroll
            for (int ct = 0; ct < 8; ct++)
                bnext[ct] = *reinterpret_cast<const half8*>(
                    &W1T[(size_t)(ct * 16 + l16) * IN_F + ktn + quad * 8]);
        }

        half8 afrag[2];
#pragma unroll
        for (int r = 0; r < 2; r++)
            afrag[r] = *reinterpret_cast<const half8*>(
                &As[cur][(wave * 32 + r * 16 + l16) * APAD + quad * 8]);
#pragma unroll
        for (int r = 0; r < 2; r++)
#pragma unroll
            for (int ct = 0; ct < 8; ct++)
                acc[r][ct] = __builtin_amdgcn_mfma_f32_16x16x32_f16(afrag[r], bfrag[ct], acc[r][ct], 0, 0, 0);

        if (more) {
            half8 h0, h1;
            h0[0]=(_Float16)vb[0].x; h0[1]=(_Float16)vb[0].y; h0[2]=(_Float16)vb[0].z; h0[3]=(_Float16)vb[0].w;
            h0[4]=(_Float16)vb[1].x; h0[5]=(_Float16)vb[1].y; h0[6]=(_Float16)vb[1].z; h0[7]=(_Float16)vb[1].w;
            h1[0]=(_Float16)vb[2].x; h1[1]=(_Float16)vb[2].y; h1[2]=(_Float16)vb[2].z; h1[3]=(_Float16)vb[2].w;
            h1[4]=(_Float16)vb[3].x; h1[5]=(_Float16)vb[3].y; h1[6]=(_Float16)vb[3].z; h1[7]=(_Float16)vb[3].w;
            *reinterpret_cast<half8*>(&As[cur ^ 1][srow * APAD + sc16 + 0]) = h0;
            *reinterpret_cast<half8*>(&As[cur ^ 1][srow * APAD + sc16 + 8]) = h1;
#pragma unroll
            for (int ct = 0; ct < 8; ct++) bfrag[ct] = bnext[ct];
        }
        cur ^= 1;
    }

#pragma unroll
    for (int r = 0; r < 2; r++) {
#pragma unroll
        for (int i = 0; i < 4; i++) {
            int grow = m0 + wave * 32 + r * 16 + quad * 4 + i;
            if (grow < N_NODES) {
                float s = norm_src[grow];
                _Float16* orow = &xwh[(size_t)grow * HID];
#pragma unroll
                for (int ct = 0; ct < 8; ct++)
                    orow[ct * 16 + l16] = (_Float16)(acc[r][ct][i] * s);
            }
        }
    }
}

// ---------------- fused gather1 + relu + layer2 GEMV: one wave per node ----------------
__global__ __launch_bounds__(256) void gather1_kernel(
        const int* __restrict__ csr, const int* __restrict__ offs,
        const _Float16* __restrict__ xwh, const float* __restrict__ norm_dst,
        const float* __restrict__ norm_src, const float* __restrict__ b1,
        const float* __restrict__ W2, float* __restrict__ hw2) {
    const int w    = (blockIdx.x * blockDim.x + threadIdx.x) >> 6;
    const int lane = threadIdx.x & 63;
    if (w >= N_NODES) return;
    const int off = offs[w], end = offs[w + 1];
    const int j2 = lane * 2;

    float a0 = 0.f, a1 = 0.f;
    int k = off;
    for (; k + 4 <= end; k += 4) {
        int s0 = csr[k], s1 = csr[k + 1], s2 = csr[k + 2], s3 = csr[k + 3];
        half2v v0 = *reinterpret_cast<const half2v*>(&xwh[(size_t)s0 * HID + j2]);
        half2v v1 = *reinterpret_cast<const half2v*>(&xwh[(size_t)s1 * HID + j2]);
        half2v v2 = *reinterpret_cast<const half2v*>(&xwh[(size_t)s2 * HID + j2]);
        half2v v3 = *reinterpret_cast<const half2v*>(&xwh[(size_t)s3 * HID + j2]);
        a0 += (float)v0[0] + (float)v1[0] + (float)v2[0] + (float)v3[0];
        a1 += (float)v0[1] + (float)v1[1] + (float)v2[1] + (float)v3[1];
    }
    for (; k < end; k++) {
        half2v v = *reinterpret_cast<const half2v*>(&xwh[(size_t)csr[k] * HID + j2]);
        a0 += (float)v[0]; a1 += (float)v[1];
    }

    const float nd = norm_dst[w];
    float2 b = *reinterpret_cast<const float2*>(&b1[j2]);
    float h0 = fmaxf(a0 * nd + b.x, 0.f);
    float h1 = fmaxf(a1 * nd + b.y, 0.f);
    float2 w2a = reinterpret_cast<const float2*>(W2)[j2];
    float2 w2b = reinterpret_cast<const float2*>(W2)[j2 + 1];
    float p0 = h0 * w2a.x + h1 * w2b.x;
    float p1 = h0 * w2a.y + h1 * w2b.y;
#pragma unroll
    for (int offd = 32; offd > 0; offd >>= 1) {
        p0 += __shfl_down(p0, offd);
        p1 += __shfl_down(p1, offd);
    }
    if (lane == 0) {
        float ns = norm_src[w];
        reinterpret_cast<float2*>(hw2)[w] = make_float2(p0 * ns, p1 * ns);
    }
}

// ---------------- fused gather2 + softmax: 4 nodes per wave (16 lanes each) ----------------
__global__ void gather2_softmax_kernel(
        const int* __restrict__ csr, const int* __restrict__ offs,
        const float* __restrict__ hw2, const float* __restrict__ norm_dst,
        const float* __restrict__ b2, float* __restrict__ out) {
    const int w    = (blockIdx.x * blockDim.x + threadIdx.x) >> 6;
    const int lane = threadIdx.x & 63;
    const int sub  = lane >> 4, k0 = lane & 15;
    const int n = w * 4 + sub;
    if (n >= N_NODES) return;
    const int off = offs[n], end = offs[n + 1];

    float a0 = 0.f, a1 = 0.f;
    for (int k = off + k0; k < end; k += 16) {
        int s = csr[k];
        float2 v = reinterpret_cast<const float2*>(hw2)[s];
        a0 += v.x; a1 += v.y;
    }
#pragma unroll
    for (int d = 1; d < 16; d <<= 1) {
        a0 += __shfl_xor(a0, d);
        a1 += __shfl_xor(a1, d);
    }
    if (k0 == 0) {
        float nd = norm_dst[n];
        float z0 = a0 * nd + b2[0];
        float z1 = a1 * nd + b2[1];
        float m = fmaxf(z0, z1);
        float e0 = expf(z0 - m), e1 = expf(z1 - m);
        float inv = 1.f / (e0 + e1);
        reinterpret_cast<float2*>(out)[n] = make_float2(e0 * inv, e1 * inv);
    }
}

extern "C" void kernel_launch(void* const* d_in, const int* in_sizes, int n_in,
                              void* d_out, int out_size, void* d_ws, size_t ws_size,
                              hipStream_t stream) {
    const float* X   = (const float*)d_in[0];
    const float* W1  = (const float*)d_in[1];
    const float* b1  = (const float*)d_in[2];
    const float* W2  = (const float*)d_in[3];
    const float* b2  = (const float*)d_in[4];
    const int*   src = (const int*)d_in[5];
    const int*   dst = (const int*)d_in[6];
    float* out = (float*)d_out;

    const size_t N = N_NODES;
    char* ws = (char*)d_ws;
    // zeroed region first: 8-copy sharded degree counters
    int*   outdeg8  = (int*)ws;                       ws += 8 * N * 4;   // 3.2 MB
    int*   indeg8   = (int*)ws;                       ws += 8 * N * 4;   // 3.2 MB
    size_t zero_bytes = (char*)ws - (char*)d_ws;
    int*   rank     = (int*)ws;                       ws += (size_t)N_EDGES * 4;   // 6.4 MB
    int*   cbase    = (int*)ws;                       ws += 8 * N * 4;   // 3.2 MB
    int*   indeg_t  = (int*)ws;                       ws += N * 4;
    int*   offs     = (int*)ws;                       ws += (N + 1) * 4;
    int*   bsum     = (int*)ws;                       ws += NBLK * 4;
    int*   bbase    = (int*)ws;                       ws += NBLK * 4;
    float* norm_src = (float*)ws;                     ws += N * 4;
    float* norm_dst = (float*)ws;                     ws += N * 4;
    float* hw2      = (float*)ws;                     ws += N * 2 * 4;
    _Float16* W1T   = (_Float16*)ws;                  ws += (size_t)IN_F * HID * 2; // 128 KB
    _Float16* xwh   = (_Float16*)ws;                  ws += N * (size_t)HID * 2;    // 25.6 MB
    int*   csr      = (int*)ws;                       ws += (size_t)N_EDGES * 4;    // 6.4 MB

    hipMemsetAsync(d_ws, 0, zero_bytes, stream);

    rank_kernel<<<(N_EDGES + 255) / 256, 256, 0, stream>>>(src, dst, outdeg8, indeg8, rank);
    merge_kernel<<<NBLK, 256, 0, stream>>>(outdeg8, indeg8, norm_src, norm_dst, cbase, indeg_t);
    scanA_kernel<<<NBLK, 256, 0, stream>>>(indeg_t, bsum);
    scanB_kernel<<<1, 512, 0, stream>>>(bsum, bbase);
    scanC_kernel<<<NBLK, 256, 0, stream>>>(indeg_t, bbase, offs);
    scatter_csr_kernel<<<(N_EDGES + 255) / 256, 256, 0, stream>>>(src, dst, rank, offs, cbase, csr);
    cvtW1_kernel<<<(IN_F * HID + 255) / 256, 256, 0, stream>>>(W1, W1T);
    gemm1_mfma_kernel<<<(N_NODES + 127) / 128, 256, 0, stream>>>(X, W1T, norm_src, xwh);
    gather1_kernel<<<(N_NODES * 64 + 255) / 256, 256, 0, stream>>>(
        csr, offs, xwh, norm_dst, norm_src, b1, W2, hw2);
    gather2_softmax_kernel<<<((N + 3) / 4 * 64 + 255) / 256, 256, 0, stream>>>(
        csr, offs, hw2, norm_dst, b2, out);
}

// Round 6
// 523.641 us; speedup vs baseline: 1.1619x; 1.1619x over previous
//
#include <hip/hip_runtime.h>
#include <math.h>

#define N_NODES 100000
#define N_EDGES 1600000
#define IN_F    512
#define HID     128

#define SH      8                       // nodes-per-bin shift
#define NPB     256                     // nodes per bin
#define BINS    ((N_NODES + NPB - 1) / NPB)   // 391
#define CBLK    256                     // edge-chunk blocks
#define EPB     ((N_EDGES + CBLK - 1) / CBLK) // 6250

typedef __attribute__((ext_vector_type(8))) _Float16 half8;
typedef __attribute__((ext_vector_type(2))) _Float16 half2v;
typedef __attribute__((ext_vector_type(4))) float float4v;

// ---------------- pass 1: per-block LDS histograms over dst-bins and src-bins ----------------
__global__ __launch_bounds__(256) void hist_kernel(const int* __restrict__ src,
                                                   const int* __restrict__ dst,
                                                   int* __restrict__ dbh, int* __restrict__ sbh) {
    __shared__ int hd[BINS], hs[BINS];
    const int t = threadIdx.x, blk = blockIdx.x;
    for (int i = t; i < BINS; i += 256) { hd[i] = 0; hs[i] = 0; }
    __syncthreads();
    const int e0 = blk * EPB, e1 = min(N_EDGES, e0 + EPB);
    for (int e = e0 + t; e < e1; e += 256) {
        atomicAdd(&hd[dst[e] >> SH], 1);
        atomicAdd(&hs[src[e] >> SH], 1);
    }
    __syncthreads();
    for (int i = t; i < BINS; i += 256) {
        dbh[i * CBLK + blk] = hd[i];
        sbh[i * CBLK + blk] = hs[i];
    }
}

// ---------------- pass 2a: per-bin exclusive scan over the 256 block counts ----------------
__global__ __launch_bounds__(256) void binscan_kernel(int* __restrict__ dbh, int* __restrict__ sbh,
                                                      int* __restrict__ dtot, int* __restrict__ stot) {
    __shared__ int sh[256];
    const int b = blockIdx.x, t = threadIdx.x;
    int* arr; int* tot;
    if (b < BINS) { arr = dbh + (size_t)b * CBLK; tot = &dtot[b]; }
    else          { arr = sbh + (size_t)(b - BINS) * CBLK; tot = &stot[b - BINS]; }
    int v = arr[t];
    sh[t] = v; __syncthreads();
#pragma unroll
    for (int d = 1; d < 256; d <<= 1) {
        int u = (t >= d) ? sh[t - d] : 0;
        __syncthreads();
        sh[t] += u;
        __syncthreads();
    }
    arr[t] = sh[t] - v;               // exclusive prefix within bin
    if (t == 255) *tot = sh[255];     // bin total
}

// ---------------- pass 2b: scan bin totals -> bin bases (both sides) ----------------
__global__ __launch_bounds__(512) void binbase_kernel(const int* __restrict__ dtot,
                                                      const int* __restrict__ stot,
                                                      int* __restrict__ dbase, int* __restrict__ sbase,
                                                      int* __restrict__ offs) {
    __shared__ int sh[512];
    const int t = threadIdx.x;
    int v = (t < BINS) ? dtot[t] : 0;
    sh[t] = v; __syncthreads();
#pragma unroll
    for (int d = 1; d < 512; d <<= 1) {
        int u = (t >= d) ? sh[t - d] : 0;
        __syncthreads();
        sh[t] += u;
        __syncthreads();
    }
    if (t < BINS) dbase[t] = sh[t] - v;
    if (t == BINS - 1) { dbase[BINS] = sh[t]; offs[N_NODES] = sh[t]; }
    __syncthreads();
    int v2 = (t < BINS) ? stot[t] : 0;
    sh[t] = v2; __syncthreads();
#pragma unroll
    for (int d = 1; d < 512; d <<= 1) {
        int u = (t >= d) ? sh[t - d] : 0;
        __syncthreads();
        sh[t] += u;
        __syncthreads();
    }
    if (t < BINS) sbase[t] = sh[t] - v2;
    if (t == BINS - 1) sbase[BINS] = sh[t];
}

// ---------------- pass 3: scatter edges into bin-sorted arrays (LDS cursors only) ----------------
__global__ __launch_bounds__(256) void scatter_bins_kernel(const int* __restrict__ src,
                                                           const int* __restrict__ dst,
                                                           const int* __restrict__ dbh,
                                                           const int* __restrict__ sbh,
                                                           const int* __restrict__ dbase,
                                                           const int* __restrict__ sbase,
                                                           int* __restrict__ ds_dst,
                                                           int* __restrict__ ds_src,
                                                           int* __restrict__ ss_src) {
    __shared__ int dcur[BINS], scur[BINS];
    const int t = threadIdx.x, blk = blockIdx.x;
    for (int i = t; i < BINS; i += 256) {
        dcur[i] = dbase[i] + dbh[i * CBLK + blk];
        scur[i] = sbase[i] + sbh[i * CBLK + blk];
    }
    __syncthreads();
    const int e0 = blk * EPB, e1 = min(N_EDGES, e0 + EPB);
    for (int e = e0 + t; e < e1; e += 256) {
        int d = dst[e], s = src[e];
        int p = atomicAdd(&dcur[d >> SH], 1);
        ds_dst[p] = d; ds_src[p] = s;
        int q = atomicAdd(&scur[s >> SH], 1);
        ss_src[q] = s;
    }
}

// ---------------- pass 4: per-bin counting sort -> indeg/offs/norms/CSR ----------------
__global__ __launch_bounds__(256) void finalize_kernel(const int* __restrict__ ds_dst,
                                                       const int* __restrict__ ds_src,
                                                       const int* __restrict__ ss_src,
                                                       const int* __restrict__ dbase,
                                                       const int* __restrict__ sbase,
                                                       int* __restrict__ csr, int* __restrict__ offs,
                                                       float* __restrict__ norm_dst,
                                                       float* __restrict__ norm_src) {
    __shared__ int cnt[NPB], pos[NPB];
    const int t = threadIdx.x, b = blockIdx.x;
    if (b < BINS) {
        const int start = dbase[b], end = dbase[b + 1];
        cnt[t] = 0; __syncthreads();
        for (int k = start + t; k < end; k += 256)
            atomicAdd(&cnt[ds_dst[k] & (NPB - 1)], 1);
        __syncthreads();
        const int c = cnt[t];
        pos[t] = c; __syncthreads();
#pragma unroll
        for (int d = 1; d < 256; d <<= 1) {
            int u = (t >= d) ? pos[t - d] : 0;
            __syncthreads();
            pos[t] += u;
            __syncthreads();
        }
        const int excl = pos[t] - c;
        const int node = (b << SH) + t;
        if (node < N_NODES) {
            offs[node] = start + excl;
            norm_dst[node] = rsqrtf(fmaxf((float)c, 1.0f));
        }
        cnt[t] = start + excl;      // reuse as scatter cursor
        __syncthreads();
        for (int k = start + t; k < end; k += 256) {
            int dl = ds_dst[k] & (NPB - 1);
            int p = atomicAdd(&cnt[dl], 1);
            csr[p] = ds_src[k];
        }
    } else {
        const int bb = b - BINS;
        const int start = sbase[bb], end = sbase[bb + 1];
        cnt[t] = 0; __syncthreads();
        for (int k = start + t; k < end; k += 256)
            atomicAdd(&cnt[ss_src[k] & (NPB - 1)], 1);
        __syncthreads();
        const int node = (bb << SH) + t;
        if (node < N_NODES)
            norm_src[node] = rsqrtf(fmaxf((float)cnt[t], 1.0f));
    }
}

// ---------------- W1 -> f16, transposed to [col][k] ----------------
__global__ void cvtW1_kernel(const float* __restrict__ W1, _Float16* __restrict__ W1T) {
    int i = blockIdx.x * blockDim.x + threadIdx.x;
    if (i < IN_F * HID) {
        int k = i >> 7, c = i & 127;
        W1T[(size_t)c * IN_F + k] = (_Float16)W1[i];
    }
}

// ---------------- GEMM1 via MFMA f16, double-buffered, f16 output ----------------
#define APAD 40
__global__ __launch_bounds__(256) void gemm1_mfma_kernel(const float* __restrict__ X,
                                                         const _Float16* __restrict__ W1T,
                                                         const float* __restrict__ norm_src,
                                                         _Float16* __restrict__ xwh) {
    __shared__ _Float16 As[2][128 * APAD];

    const int t    = threadIdx.x;
    const int wave = t >> 6;
    const int lane = t & 63;
    const int m0   = blockIdx.x * 128;
    const int quad = lane >> 4;
    const int l16  = lane & 15;

    float4v acc[2][8];
#pragma unroll
    for (int r = 0; r < 2; r++)
#pragma unroll
        for (int c = 0; c < 8; c++) acc[r][c] = (float4v)0.f;

    const int srow = t >> 1;
    const int sc16 = (t & 1) * 16;
    const int sgrow = m0 + srow;
    const bool svalid = sgrow < N_NODES;
    const float* xbase = X + (size_t)sgrow * IN_F + sc16;

    float4 va[4];
#pragma unroll
    for (int i = 0; i < 4; i++) va[i] = make_float4(0.f, 0.f, 0.f, 0.f);
    if (svalid) {
        const float4* xp = reinterpret_cast<const float4*>(xbase);
        va[0] = xp[0]; va[1] = xp[1]; va[2] = xp[2]; va[3] = xp[3];
    }
    half8 bfrag[8];
#pragma unroll
    for (int ct = 0; ct < 8; ct++)
        bfrag[ct] = *reinterpret_cast<const half8*>(&W1T[(size_t)(ct * 16 + l16) * IN_F + quad * 8]);

    {
        half8 h0, h1;
        h0[0]=(_Float16)va[0].x; h0[1]=(_Float16)va[0].y; h0[2]=(_Float16)va[0].z; h0[3]=(_Float16)va[0].w;
        h0[4]=(_Float16)va[1].x; h0[5]=(_Float16)va[1].y; h0[6]=(_Float16)va[1].z; h0[7]=(_Float16)va[1].w;
        h1[0]=(_Float16)va[2].x; h1[1]=(_Float16)va[2].y; h1[2]=(_Float16)va[2].z; h1[3]=(_Float16)va[2].w;
        h1[4]=(_Float16)va[3].x; h1[5]=(_Float16)va[3].y; h1[6]=(_Float16)va[3].z; h1[7]=(_Float16)va[3].w;
        *reinterpret_cast<half8*>(&As[0][srow * APAD + sc16 + 0]) = h0;
        *reinterpret_cast<half8*>(&As[0][srow * APAD + sc16 + 8]) = h1;
    }

    int cur = 0;
    for (int it = 0; it < IN_F / 32; it++) {
        const int ktn = (it + 1) * 32;
        const bool more = ktn < IN_F;
        __syncthreads();

        float4 vb[4];
        half8 bnext[8];
        if (more) {
            if (svalid) {
                const float4* xp = reinterpret_cast<const float4*>(xbase + ktn);
                vb[0] = xp[0]; vb[1] = xp[1]; vb[2] = xp[2]; vb[3] = xp[3];
            } else {
                vb[0] = vb[1] = vb[2] = vb[3] = make_float4(0.f, 0.f, 0.f, 0.f);
            }
#pragma unroll
            for (int ct = 0; ct < 8; ct++)
                bnext[ct] = *reinterpret_cast<const half8*>(
                    &W1T[(size_t)(ct * 16 + l16) * IN_F + ktn + quad * 8]);
        }

        half8 afrag[2];
#pragma unroll
        for (int r = 0; r < 2; r++)
            afrag[r] = *reinterpret_cast<const half8*>(
                &As[cur][(wave * 32 + r * 16 + l16) * APAD + quad * 8]);
#pragma unroll
        for (int r = 0; r < 2; r++)
#pragma unroll
            for (int ct = 0; ct < 8; ct++)
                acc[r][ct] = __builtin_amdgcn_mfma_f32_16x16x32_f16(afrag[r], bfrag[ct], acc[r][ct], 0, 0, 0);

        if (more) {
            half8 h0, h1;
            h0[0]=(_Float16)vb[0].x; h0[1]=(_Float16)vb[0].y; h0[2]=(_Float16)vb[0].z; h0[3]=(_Float16)vb[0].w;
            h0[4]=(_Float16)vb[1].x; h0[5]=(_Float16)vb[1].y; h0[6]=(_Float16)vb[1].z; h0[7]=(_Float16)vb[1].w;
            h1[0]=(_Float16)vb[2].x; h1[1]=(_Float16)vb[2].y; h1[2]=(_Float16)vb[2].z; h1[3]=(_Float16)vb[2].w;
            h1[4]=(_Float16)vb[3].x; h1[5]=(_Float16)vb[3].y; h1[6]=(_Float16)vb[3].z; h1[7]=(_Float16)vb[3].w;
            *reinterpret_cast<half8*>(&As[cur ^ 1][srow * APAD + sc16 + 0]) = h0;
            *reinterpret_cast<half8*>(&As[cur ^ 1][srow * APAD + sc16 + 8]) = h1;
#pragma unroll
            for (int ct = 0; ct < 8; ct++) bfrag[ct] = bnext[ct];
        }
        cur ^= 1;
    }

#pragma unroll
    for (int r = 0; r < 2; r++) {
#pragma unroll
        for (int i = 0; i < 4; i++) {
            int grow = m0 + wave * 32 + r * 16 + quad * 4 + i;
            if (grow < N_NODES) {
                float s = norm_src[grow];
                _Float16* orow = &xwh[(size_t)grow * HID];
#pragma unroll
                for (int ct = 0; ct < 8; ct++)
                    orow[ct * 16 + l16] = (_Float16)(acc[r][ct][i] * s);
            }
        }
    }
}

// ---------------- fused gather1 + relu + layer2 GEMV: one wave per node ----------------
__global__ __launch_bounds__(256) void gather1_kernel(
        const int* __restrict__ csr, const int* __restrict__ offs,
        const _Float16* __restrict__ xwh, const float* __restrict__ norm_dst,
        const float* __restrict__ norm_src, const float* __restrict__ b1,
        const float* __restrict__ W2, float* __restrict__ hw2) {
    const int w    = (blockIdx.x * blockDim.x + threadIdx.x) >> 6;
    const int lane = threadIdx.x & 63;
    if (w >= N_NODES) return;
    const int off = offs[w], end = offs[w + 1];
    const int j2 = lane * 2;

    float a0 = 0.f, a1 = 0.f;
    int k = off;
    for (; k + 4 <= end; k += 4) {
        int s0 = csr[k], s1 = csr[k + 1], s2 = csr[k + 2], s3 = csr[k + 3];
        half2v v0 = *reinterpret_cast<const half2v*>(&xwh[(size_t)s0 * HID + j2]);
        half2v v1 = *reinterpret_cast<const half2v*>(&xwh[(size_t)s1 * HID + j2]);
        half2v v2 = *reinterpret_cast<const half2v*>(&xwh[(size_t)s2 * HID + j2]);
        half2v v3 = *reinterpret_cast<const half2v*>(&xwh[(size_t)s3 * HID + j2]);
        a0 += (float)v0[0] + (float)v1[0] + (float)v2[0] + (float)v3[0];
        a1 += (float)v0[1] + (float)v1[1] + (float)v2[1] + (float)v3[1];
    }
    for (; k < end; k++) {
        half2v v = *reinterpret_cast<const half2v*>(&xwh[(size_t)csr[k] * HID + j2]);
        a0 += (float)v[0]; a1 += (float)v[1];
    }

    const float nd = norm_dst[w];
    float2 b = *reinterpret_cast<const float2*>(&b1[j2]);
    float h0 = fmaxf(a0 * nd + b.x, 0.f);
    float h1 = fmaxf(a1 * nd + b.y, 0.f);
    float2 w2a = reinterpret_cast<const float2*>(W2)[j2];
    float2 w2b = reinterpret_cast<const float2*>(W2)[j2 + 1];
    float p0 = h0 * w2a.x + h1 * w2b.x;
    float p1 = h0 * w2a.y + h1 * w2b.y;
#pragma unroll
    for (int offd = 32; offd > 0; offd >>= 1) {
        p0 += __shfl_down(p0, offd);
        p1 += __shfl_down(p1, offd);
    }
    if (lane == 0) {
        float ns = norm_src[w];
        reinterpret_cast<float2*>(hw2)[w] = make_float2(p0 * ns, p1 * ns);
    }
}

// ---------------- fused gather2 + softmax: 4 nodes per wave (16 lanes each) ----------------
__global__ void gather2_softmax_kernel(
        const int* __restrict__ csr, const int* __restrict__ offs,
        const float* __restrict__ hw2, const float* __restrict__ norm_dst,
        const float* __restrict__ b2, float* __restrict__ out) {
    const int w    = (blockIdx.x * blockDim.x + threadIdx.x) >> 6;
    const int lane = threadIdx.x & 63;
    const int sub  = lane >> 4, k0 = lane & 15;
    const int n = w * 4 + sub;
    if (n >= N_NODES) return;
    const int off = offs[n], end = offs[n + 1];

    float a0 = 0.f, a1 = 0.f;
    for (int k = off + k0; k < end; k += 16) {
        int s = csr[k];
        float2 v = reinterpret_cast<const float2*>(hw2)[s];
        a0 += v.x; a1 += v.y;
    }
#pragma unroll
    for (int d = 1; d < 16; d <<= 1) {
        a0 += __shfl_xor(a0, d);
        a1 += __shfl_xor(a1, d);
    }
    if (k0 == 0) {
        float nd = norm_dst[n];
        float z0 = a0 * nd + b2[0];
        float z1 = a1 * nd + b2[1];
        float m = fmaxf(z0, z1);
        float e0 = expf(z0 - m), e1 = expf(z1 - m);
        float inv = 1.f / (e0 + e1);
        reinterpret_cast<float2*>(out)[n] = make_float2(e0 * inv, e1 * inv);
    }
}

extern "C" void kernel_launch(void* const* d_in, const int* in_sizes, int n_in,
                              void* d_out, int out_size, void* d_ws, size_t ws_size,
                              hipStream_t stream) {
    const float* X   = (const float*)d_in[0];
    const float* W1  = (const float*)d_in[1];
    const float* b1  = (const float*)d_in[2];
    const float* W2  = (const float*)d_in[3];
    const float* b2  = (const float*)d_in[4];
    const int*   src = (const int*)d_in[5];
    const int*   dst = (const int*)d_in[6];
    float* out = (float*)d_out;

    const size_t N = N_NODES;
    char* ws = (char*)d_ws;
    int*   dbh      = (int*)ws;   ws += (size_t)BINS * CBLK * 4;   // 400 KB
    int*   sbh      = (int*)ws;   ws += (size_t)BINS * CBLK * 4;   // 400 KB
    int*   dtot     = (int*)ws;   ws += BINS * 4;
    int*   stot     = (int*)ws;   ws += BINS * 4;
    int*   dbase    = (int*)ws;   ws += (BINS + 1) * 4;
    int*   sbase    = (int*)ws;   ws += (BINS + 1) * 4;
    int*   ds_dst   = (int*)ws;   ws += (size_t)N_EDGES * 4;       // 6.4 MB
    int*   ds_src   = (int*)ws;   ws += (size_t)N_EDGES * 4;       // 6.4 MB
    int*   ss_src   = (int*)ws;   ws += (size_t)N_EDGES * 4;       // 6.4 MB
    int*   csr      = (int*)ws;   ws += (size_t)N_EDGES * 4;       // 6.4 MB
    int*   offs     = (int*)ws;   ws += (N + 1) * 4;
    float* norm_src = (float*)ws; ws += N * 4;
    float* norm_dst = (float*)ws; ws += N * 4;
    float* hw2      = (float*)ws; ws += N * 2 * 4;
    _Float16* W1T   = (_Float16*)ws; ws += (size_t)IN_F * HID * 2; // 128 KB
    _Float16* xwh   = (_Float16*)ws; ws += N * (size_t)HID * 2;    // 25.6 MB

    // no memset needed: every buffer is fully written before it is read
    hist_kernel<<<CBLK, 256, 0, stream>>>(src, dst, dbh, sbh);
    binscan_kernel<<<2 * BINS, 256, 0, stream>>>(dbh, sbh, dtot, stot);
    binbase_kernel<<<1, 512, 0, stream>>>(dtot, stot, dbase, sbase, offs);
    scatter_bins_kernel<<<CBLK, 256, 0, stream>>>(src, dst, dbh, sbh, dbase, sbase,
                                                  ds_dst, ds_src, ss_src);
    finalize_kernel<<<2 * BINS, 256, 0, stream>>>(ds_dst, ds_src, ss_src, dbase, sbase,
                                                  csr, offs, norm_dst, norm_src);
    cvtW1_kernel<<<(IN_F * HID + 255) / 256, 256, 0, stream>>>(W1, W1T);
    gemm1_mfma_kernel<<<(N_NODES + 127) / 128, 256, 0, stream>>>(X, W1T, norm_src, xwh);
    gather1_kernel<<<(N_NODES * 64 + 255) / 256, 256, 0, stream>>>(
        csr, offs, xwh, norm_dst, norm_src, b1, W2, hw2);
    gather2_softmax_kernel<<<(((int)N + 3) / 4 * 64 + 255) / 256, 256, 0, stream>>>(
        csr, offs, hw2, norm_dst, b2, out);
}